// Round 5
// baseline (2669.405 us; speedup 1.0000x reference)
//
#include <hip/hip_runtime.h>

typedef unsigned int u32;
typedef unsigned short u16;
typedef short bf16x8 __attribute__((ext_vector_type(8)));
typedef float f32x4 __attribute__((ext_vector_type(4)));

#define S1 12544      // 112*112
#define NSTAT 200704  // 16*112*112
#define EPS 1e-5f
#define AP 264        // padded A-tile row length (fused path)

__device__ __forceinline__ u16 f2bf(float f) {
  union { float f; u32 u; } x; x.f = f;
  u32 r = x.u + 0x7fffu + ((x.u >> 16) & 1u);
  return (u16)(r >> 16);
}
__device__ __forceinline__ void bf2x2(u32 u, float& lo, float& hi) {
  union { u32 u; float f; } a, b;
  a.u = u << 16; b.u = u & 0xffff0000u;
  lo = a.f; hi = b.f;
}
__device__ __forceinline__ float sigm(float x) { return 1.f / (1.f + expf(-x)); }

// ---------------- conv1 (3->256, 3x3, stride2, pad1) + bn1 stats ----------------
#define CW 225
__global__ __launch_bounds__(256) void k_conv1(const float* __restrict__ img,
    const float* __restrict__ w, u16* __restrict__ out, float* __restrict__ stats) {
  int blk = blockIdx.x;
  int b = blk / 56, strip = blk - b * 56;
  int r0 = strip * 2;
  int c = threadIdx.x;
  __shared__ float simg[3 * 5 * CW];
  const float* ib = img + (size_t)b * 3 * 224 * 224;
  for (int i = c; i < 3 * 5 * CW; i += 256) {
    int ch = i / (5 * CW);
    int rem = i - ch * (5 * CW);
    int lr = rem / CW;
    int col = rem - lr * CW;
    int ih = 2 * r0 - 1 + lr;
    int iw = col - 1;
    float v = 0.f;
    if (ih >= 0 && ih < 224 && iw >= 0 && iw < 224) v = ib[((size_t)ch * 224 + ih) * 224 + iw];
    simg[i] = v;
  }
  float wr[27];
#pragma unroll
  for (int i = 0; i < 27; i++) wr[i] = w[c * 27 + i];
  __syncthreads();
  float s = 0.f, q = 0.f;
  for (int orow = 0; orow < 2; orow++) {
    int oh = r0 + orow;
    for (int ow = 0; ow < 112; ow++) {
      float acc = 0.f;
#pragma unroll
      for (int ch = 0; ch < 3; ch++)
#pragma unroll
        for (int dr = 0; dr < 3; dr++) {
          const float* rp = &simg[(ch * 5 + 2 * orow + dr) * CW + 2 * ow];
          acc = fmaf(wr[(ch * 3 + dr) * 3 + 0], rp[0], acc);
          acc = fmaf(wr[(ch * 3 + dr) * 3 + 1], rp[1], acc);
          acc = fmaf(wr[(ch * 3 + dr) * 3 + 2], rp[2], acc);
        }
      s += acc; q = fmaf(acc, acc, q);
      out[((size_t)(b * 112 + oh) * 112 + ow) * 256 + c] = f2bf(acc);
    }
  }
  atomicAdd(&stats[c], s);
  atomicAdd(&stats[256 + c], q);
}

// ---------------- bn finalize ----------------
__global__ void k_bnfin(const float* __restrict__ stats, const float* __restrict__ g,
                        const float* __restrict__ bb, float* __restrict__ par, int C, float invN) {
  int c = blockIdx.x * 256 + threadIdx.x;
  if (c < C) {
    float m = stats[c] * invN;
    float v = stats[C + c] * invN - m * m;
    float sc = g[c] * rsqrtf(v + EPS);
    par[c] = sc;
    par[C + c] = bb[c] - m * sc;
  }
}

// ---------------- fp32 -> bf16 x4 ----------------
__global__ void k_cvt4(const float* __restrict__ w, u16* __restrict__ o, int n4) {
  int i = blockIdx.x * 256 + threadIdx.x;
  if (i < n4) {
    float4 v = ((const float4*)w)[i];
    union { u16 h[4]; uint2 u; } pk;
    pk.h[0] = f2bf(v.x); pk.h[1] = f2bf(v.y); pk.h[2] = f2bf(v.z); pk.h[3] = f2bf(v.w);
    ((uint2*)o)[i] = pk.u;
  }
}

// ---- shared sliding-window dw macro (uses locals: ib, c4, sc, sh, act) ----
#define LD_COL(ohv, iwv, slot) do {                                          \
    int _oh = (ohv), _iw = (iwv);                                            \
  _Pragma("unroll")                                                          \
    for (int _dr = 0; _dr < 3; _dr++) {                                      \
      int _ih = _oh - 1 + _dr;                                               \
      float _x0 = 0.f, _x1 = 0.f, _x2 = 0.f, _x3 = 0.f;                      \
      if (_ih >= 0 && _ih < 112 && _iw >= 0 && _iw < 112) {                  \
        uint2 _v = *(const uint2*)(ib + ((size_t)(_ih * 112 + _iw)) * 256 + c4); \
        float _t0, _t1, _t2, _t3;                                            \
        bf2x2(_v.x, _t0, _t1); bf2x2(_v.y, _t2, _t3);                        \
        _x0 = fmaxf(fmaf(_t0, sc[0], sh[0]), 0.f);                           \
        _x1 = fmaxf(fmaf(_t1, sc[1], sh[1]), 0.f);                           \
        _x2 = fmaxf(fmaf(_t2, sc[2], sh[2]), 0.f);                           \
        _x3 = fmaxf(fmaf(_t3, sc[3], sh[3]), 0.f);                           \
      }                                                                      \
      act[_dr][slot][0] = _x0; act[_dr][slot][1] = _x1;                      \
      act[_dr][slot][2] = _x2; act[_dr][slot][3] = _x3;                      \
    }                                                                        \
  } while (0)

// ---------------- standalone dw kernel (big-ws path): conv1out -> dwout bf16 ----------------
__global__ __launch_bounds__(256) void k_dws(const u16* __restrict__ cin,
    const float* __restrict__ bn1p, const float* __restrict__ dww, u16* __restrict__ out) {
  int tid = threadIdx.x;
  int wave = tid >> 6, lane = tid & 63;
  int c4 = lane * 4;
  int m0 = blockIdx.x * 64;
  int bimg = blockIdx.x / 196;
  float sc[4], sh[4], w9[4][9];
#pragma unroll
  for (int cc = 0; cc < 4; cc++) {
    sc[cc] = bn1p[c4 + cc];
    sh[cc] = bn1p[256 + c4 + cc];
#pragma unroll
    for (int i = 0; i < 9; i++) w9[cc][i] = dww[(c4 + cc) * 9 + i];
  }
  const u16* ib = cin + (size_t)bimg * S1 * 256;
  float act[3][3][4];
#pragma unroll
  for (int pp = 0; pp < 16; pp++) {
    int p = wave * 16 + pp;
    int s = m0 + p - bimg * S1;
    int oh = s / 112, ow = s - oh * 112;
    if (pp == 0 || ow == 0) {
      LD_COL(oh, ow - 1, (pp + 0) % 3);
      LD_COL(oh, ow,     (pp + 1) % 3);
      LD_COL(oh, ow + 1, (pp + 2) % 3);
    } else {
      LD_COL(oh, ow + 1, (pp + 2) % 3);
    }
    float a0 = 0.f, a1 = 0.f, a2 = 0.f, a3 = 0.f;
#pragma unroll
    for (int dr = 0; dr < 3; dr++)
#pragma unroll
      for (int dc = 0; dc < 3; dc++) {
        const int sl = (pp + dc) % 3;
        const int wi = dr * 3 + dc;
        a0 = fmaf(w9[0][wi], act[dr][sl][0], a0);
        a1 = fmaf(w9[1][wi], act[dr][sl][1], a1);
        a2 = fmaf(w9[2][wi], act[dr][sl][2], a2);
        a3 = fmaf(w9[3][wi], act[dr][sl][3], a3);
      }
    union { u16 h[4]; uint2 v; } pk;
    pk.h[0] = f2bf(a0); pk.h[1] = f2bf(a1);
    pk.h[2] = f2bf(a2); pk.h[3] = f2bf(a3);
    *(uint2*)(out + (size_t)(m0 + p) * 256 + c4) = pk.v;
  }
}

// ---------------- streaming pw GEMM (big-ws path): dwout[200704x256] x bwb[512x256]^T ----------------
// XOR-swizzled LDS A-tile (64x256 bf16, 32KB) -> 2-way-free bank access on b128 reads.
__global__ __launch_bounds__(256, 2) void k_pws(const u16* __restrict__ A,
    const u16* __restrict__ bwb, float* __restrict__ partials,
    const float* __restrict__ bn2p, int pass) {
  __shared__ u16 ash[64 * 256];
  int tid = threadIdx.x;
  int wave = tid >> 6, lane = tid & 63;
  int m0 = blockIdx.x * 64;
  // stage A-tile: LDS(p, g') holds global(p, g'^(p&7)), 16B groups
  {
    const char* gb = (const char*)(A + (size_t)m0 * 256);
    char* lb = (char*)ash;
#pragma unroll
    for (int i = 0; i < 8; i++) {
      int L = wave * 8192 + i * 1024 + lane * 16;
      int p = L >> 9;
      int gp = (L >> 4) & 31;
      int g = gp ^ (p & 7);
      uint4 v = *(const uint4*)(gb + (size_t)p * 512 + g * 16);
      *(uint4*)(lb + L) = v;
    }
  }
  __syncthreads();

  int quad = lane >> 4;
  int lr = lane & 15;
  int nbase = wave * 128;
  const char* ashb = (const char*)ash;
  f32x4 acc[4][8];
#pragma unroll
  for (int mt = 0; mt < 4; mt++)
#pragma unroll
    for (int nt = 0; nt < 8; nt++) acc[mt][nt] = (f32x4){0.f, 0.f, 0.f, 0.f};

#pragma unroll
  for (int ch = 0; ch < 8; ch++) {
    bf16x8 af[4];
#pragma unroll
    for (int mt = 0; mt < 4; mt++) {
      int row = mt * 16 + lr;
      int g = (ch * 4 + quad) ^ (row & 7);
      af[mt] = *(const bf16x8*)(ashb + row * 512 + g * 16);
    }
    bf16x8 bfr[8];
#pragma unroll
    for (int nt = 0; nt < 8; nt++)
      bfr[nt] = *(const bf16x8*)(bwb + (size_t)(nbase + nt * 16 + lr) * 256 + ch * 32 + quad * 8);
#pragma unroll
    for (int mt = 0; mt < 4; mt++)
#pragma unroll
      for (int nt = 0; nt < 8; nt++)
        acc[mt][nt] = __builtin_amdgcn_mfma_f32_16x16x32_bf16(af[mt], bfr[nt], acc[mt][nt], 0, 0, 0);
  }

  if (pass == 0) {
#pragma unroll
    for (int nt = 0; nt < 8; nt++) {
      float s = 0.f, q = 0.f;
#pragma unroll
      for (int mt = 0; mt < 4; mt++)
#pragma unroll
        for (int r = 0; r < 4; r++) {
          float v = acc[mt][nt][r];
          s += v; q = fmaf(v, v, q);
        }
      s += __shfl_xor(s, 16); s += __shfl_xor(s, 32);
      q += __shfl_xor(q, 16); q += __shfl_xor(q, 32);
      if (lane < 16) {
        int n = nbase + nt * 16 + lane;
        partials[(size_t)blockIdx.x * 1024 + n] = s;
        partials[(size_t)blockIdx.x * 1024 + 512 + n] = q;
      }
    }
  } else {
#pragma unroll
    for (int nt = 0; nt < 8; nt++) {
      int n = nbase + nt * 16 + lr;
      float scn = bn2p[n], shn = bn2p[512 + n];
      float s = 0.f;
#pragma unroll
      for (int mt = 0; mt < 4; mt++)
#pragma unroll
        for (int r = 0; r < 4; r++)
          s += fmaxf(fmaf(acc[mt][nt][r], scn, shn), 0.f);
      s += __shfl_xor(s, 16); s += __shfl_xor(s, 32);
      if (lane < 16)
        partials[(size_t)blockIdx.x * 512 + n] = s;
    }
  }
}

// ---------------- fused dw+pw (small-ws fallback, proven in R4) ----------------
__global__ __launch_bounds__(256, 2) void k_pwpass(
    const u16* __restrict__ conv1out, const float* __restrict__ bn1p,
    const float* __restrict__ dww, const u16* __restrict__ bwb,
    float* __restrict__ partials, const float* __restrict__ bn2p, int pass) {
  __shared__ u16 ash[64 * AP];
  int tid = threadIdx.x;
  int wave = tid >> 6;
  int lane = tid & 63;
  int m0 = blockIdx.x * 64;
  int bimg = blockIdx.x / 196;
  {
    int c4 = lane * 4;
    float sc[4], sh[4], w9[4][9];
#pragma unroll
    for (int cc = 0; cc < 4; cc++) {
      sc[cc] = bn1p[c4 + cc];
      sh[cc] = bn1p[256 + c4 + cc];
#pragma unroll
      for (int i = 0; i < 9; i++) w9[cc][i] = dww[(c4 + cc) * 9 + i];
    }
    const u16* ib = conv1out + (size_t)bimg * S1 * 256;
    float act[3][3][4];
#pragma unroll
    for (int pp = 0; pp < 16; pp++) {
      int p = wave * 16 + pp;
      int s = m0 + p - bimg * S1;
      int oh = s / 112, ow = s - oh * 112;
      if (pp == 0 || ow == 0) {
        LD_COL(oh, ow - 1, (pp + 0) % 3);
        LD_COL(oh, ow,     (pp + 1) % 3);
        LD_COL(oh, ow + 1, (pp + 2) % 3);
      } else {
        LD_COL(oh, ow + 1, (pp + 2) % 3);
      }
      float a0 = 0.f, a1 = 0.f, a2 = 0.f, a3 = 0.f;
#pragma unroll
      for (int dr = 0; dr < 3; dr++)
#pragma unroll
        for (int dc = 0; dc < 3; dc++) {
          const int sl = (pp + dc) % 3;
          const int wi = dr * 3 + dc;
          a0 = fmaf(w9[0][wi], act[dr][sl][0], a0);
          a1 = fmaf(w9[1][wi], act[dr][sl][1], a1);
          a2 = fmaf(w9[2][wi], act[dr][sl][2], a2);
          a3 = fmaf(w9[3][wi], act[dr][sl][3], a3);
        }
      union { u16 h[4]; uint2 v; } pk;
      pk.h[0] = f2bf(a0); pk.h[1] = f2bf(a1);
      pk.h[2] = f2bf(a2); pk.h[3] = f2bf(a3);
      *(uint2*)(&ash[p * AP + c4]) = pk.v;
    }
  }
  __syncthreads();
  int quad = lane >> 4;
  int lr = lane & 15;
  int nbase = wave * 128;
  f32x4 acc[4][8];
#pragma unroll
  for (int mt = 0; mt < 4; mt++)
#pragma unroll
    for (int nt = 0; nt < 8; nt++) acc[mt][nt] = (f32x4){0.f, 0.f, 0.f, 0.f};
  for (int kk = 0; kk < 256; kk += 32) {
    bf16x8 af[4];
#pragma unroll
    for (int mt = 0; mt < 4; mt++)
      af[mt] = *(const bf16x8*)(&ash[(mt * 16 + lr) * AP + kk + quad * 8]);
    bf16x8 bfr[8];
#pragma unroll
    for (int nt = 0; nt < 8; nt++)
      bfr[nt] = *(const bf16x8*)(bwb + (size_t)(nbase + nt * 16 + lr) * 256 + kk + quad * 8);
#pragma unroll
    for (int mt = 0; mt < 4; mt++)
#pragma unroll
      for (int nt = 0; nt < 8; nt++)
        acc[mt][nt] = __builtin_amdgcn_mfma_f32_16x16x32_bf16(af[mt], bfr[nt], acc[mt][nt], 0, 0, 0);
  }
  if (pass == 0) {
#pragma unroll
    for (int nt = 0; nt < 8; nt++) {
      float s = 0.f, q = 0.f;
#pragma unroll
      for (int mt = 0; mt < 4; mt++)
#pragma unroll
        for (int r = 0; r < 4; r++) {
          float v = acc[mt][nt][r];
          s += v; q = fmaf(v, v, q);
        }
      s += __shfl_xor(s, 16); s += __shfl_xor(s, 32);
      q += __shfl_xor(q, 16); q += __shfl_xor(q, 32);
      if (lane < 16) {
        int n = nbase + nt * 16 + lane;
        partials[(size_t)blockIdx.x * 1024 + n] = s;
        partials[(size_t)blockIdx.x * 1024 + 512 + n] = q;
      }
    }
  } else {
#pragma unroll
    for (int nt = 0; nt < 8; nt++) {
      int n = nbase + nt * 16 + lr;
      float scn = bn2p[n], shn = bn2p[512 + n];
      float s = 0.f;
#pragma unroll
      for (int mt = 0; mt < 4; mt++)
#pragma unroll
        for (int r = 0; r < 4; r++)
          s += fmaxf(fmaf(acc[mt][nt][r], scn, shn), 0.f);
      s += __shfl_xor(s, 16); s += __shfl_xor(s, 32);
      if (lane < 16)
        partials[(size_t)blockIdx.x * 512 + n] = s;
    }
  }
}

// ---------------- reductions ----------------
__global__ __launch_bounds__(256) void k_red1(const float* __restrict__ P, float* __restrict__ P2) {
  int blk = blockIdx.x;
  int t = threadIdx.x;
  float4 s = {0.f, 0.f, 0.f, 0.f};
  for (int r = 0; r < 49; r++) {
    float4 v = *(const float4*)(P + ((size_t)(blk * 49 + r)) * 1024 + t * 4);
    s.x += v.x; s.y += v.y; s.z += v.z; s.w += v.w;
  }
  *(float4*)(P2 + (size_t)blk * 1024 + t * 4) = s;
}

__global__ void k_red_bn2(const float* __restrict__ P2, const float* __restrict__ g,
                          const float* __restrict__ bb, float* __restrict__ par) {
  int c = blockIdx.x * 256 + threadIdx.x;
  float s = 0.f, q = 0.f;
  for (int i = 0; i < 64; i++) {
    s += P2[(size_t)i * 1024 + c];
    q += P2[(size_t)i * 1024 + 512 + c];
  }
  float m = s * (1.f / (float)NSTAT);
  float v = q * (1.f / (float)NSTAT) - m * m;
  float sc = g[c] * rsqrtf(v + EPS);
  par[c] = sc;
  par[512 + c] = bb[c] - m * sc;
}

__global__ void k_red_y(const float* __restrict__ P, float* __restrict__ yb) {
  int idx = blockIdx.x * 256 + threadIdx.x;
  int b = idx >> 9, c = idx & 511;
  float s = 0.f;
  for (int i = 0; i < 196; i++) s += P[(size_t)(b * 196 + i) * 512 + c];
  yb[idx] = s;
}

// ---------------- per-batch SE + enc_fc + ctx (ctxgi moved to k_gi) ----------------
__global__ __launch_bounds__(256) void k_se(const float* __restrict__ y,
    const float* __restrict__ se1, const float* __restrict__ se2,
    const float* __restrict__ encw, const float* __restrict__ encb,
    const float* __restrict__ vw, float* __restrict__ ctxb) {
  int b = blockIdx.x;
  int t = threadIdx.x;
  __shared__ __align__(16) float ybar[512];
  __shared__ __align__(16) float uu[128];
  __shared__ __align__(16) float ff[512];
  __shared__ __align__(16) float feats[512];
  for (int i = t; i < 512; i += 256) ybar[i] = y[b * 512 + i] * (1.f / 12544.f);
  __syncthreads();
  if (t < 128) {
    const float4* wr = (const float4*)(se1 + t * 512);
    const float4* xv = (const float4*)ybar;
    float a = 0.f;
    for (int k = 0; k < 128; k++) {
      float4 w4 = wr[k], x4 = xv[k];
      a = fmaf(w4.x, x4.x, a); a = fmaf(w4.y, x4.y, a);
      a = fmaf(w4.z, x4.z, a); a = fmaf(w4.w, x4.w, a);
    }
    uu[t] = fmaxf(a, 0.f);
  }
  __syncthreads();
  for (int c = t; c < 512; c += 256) {
    const float4* wr = (const float4*)(se2 + c * 128);
    const float4* xv = (const float4*)uu;
    float a = 0.f;
    for (int k = 0; k < 32; k++) {
      float4 w4 = wr[k], x4 = xv[k];
      a = fmaf(w4.x, x4.x, a); a = fmaf(w4.y, x4.y, a);
      a = fmaf(w4.z, x4.z, a); a = fmaf(w4.w, x4.w, a);
    }
    ff[c] = ybar[c] * sigm(a);
  }
  __syncthreads();
  for (int c = t; c < 512; c += 256) {
    const float4* wr = (const float4*)(encw + (size_t)c * 512);
    const float4* xv = (const float4*)ff;
    float a = encb[c];
    for (int k = 0; k < 128; k++) {
      float4 w4 = wr[k], x4 = xv[k];
      a = fmaf(w4.x, x4.x, a); a = fmaf(w4.y, x4.y, a);
      a = fmaf(w4.z, x4.z, a); a = fmaf(w4.w, x4.w, a);
    }
    feats[c] = a;
  }
  __syncthreads();
  for (int c = t; c < 512; c += 256) {
    const float4* wr = (const float4*)(vw + (size_t)c * 512);
    const float4* xv = (const float4*)feats;
    float a = 0.f;
    for (int k = 0; k < 128; k++) {
      float4 w4 = wr[k], x4 = xv[k];
      a = fmaf(w4.x, x4.x, a); a = fmaf(w4.y, x4.y, a);
      a = fmaf(w4.z, x4.z, a); a = fmaf(w4.w, x4.w, a);
    }
    ctxb[b * 512 + c] = a;
  }
}

// ---------------- gi = [emb_t ; ctx] @ wih^T + bih  (layout [t][b][1536]) ----------------
__global__ __launch_bounds__(256) void k_gi(const int* __restrict__ caps,
    const float* __restrict__ embed, const float* __restrict__ ctxb,
    const float* __restrict__ wih, const float* __restrict__ bih, float* __restrict__ gi) {
  int tt = blockIdx.x;   // 0..31
  int jt = blockIdx.y;   // 0..95
  int lb = threadIdx.x >> 4;
  int lj = threadIdx.x & 15;
  int j = jt * 16 + lj;
  __shared__ __align__(16) float xx[16][1024];
  for (int i = threadIdx.x; i < 16 * 512; i += 256) {
    int bb = i >> 9, k = i & 511;
    int tok = caps[bb * 33 + tt];
    xx[bb][k] = embed[(size_t)tok * 512 + k];
    xx[bb][512 + k] = ctxb[bb * 512 + k];
  }
  __syncthreads();
  const float4* wr = (const float4*)(wih + (size_t)j * 1024);
  const float4* xv = (const float4*)xx[lb];
  float a = bih[j];
#pragma unroll 4
  for (int k = 0; k < 256; k++) {
    float4 w4 = wr[k], x4 = xv[k];
    a = fmaf(w4.x, x4.x, a); a = fmaf(w4.y, x4.y, a);
    a = fmaf(w4.z, x4.z, a); a = fmaf(w4.w, x4.w, a);
  }
  gi[((size_t)tt * 16 + lb) * 1536 + j] = a;
}

// ---------------- persistent GRU: all 32 steps, device-atomic grid barrier ----------------
// 32 blocks (all co-resident on 256 CUs). block g: hidden units jj = g*16 + (tid&15).
__global__ __launch_bounds__(256, 1) void k_gru_all(const float* __restrict__ whh,
    const float* __restrict__ bhh, const float* __restrict__ gi,
    float* h_all, int* bar) {
  int g = blockIdx.x;
  int lb = threadIdx.x >> 4, lj = threadIdx.x & 15;
  int jj = g * 16 + lj;
  float bh0 = bhh[jj], bh1 = bhh[jj + 512], bh2 = bhh[jj + 1024];
  const float4* w0 = (const float4*)(whh + (size_t)jj * 512);
  const float4* w1 = (const float4*)(whh + (size_t)(jj + 512) * 512);
  const float4* w2 = (const float4*)(whh + (size_t)(jj + 1024) * 512);
  __shared__ __align__(16) float hs[16][512];
  for (int t = 0; t < 32; t++) {
    for (int i = threadIdx.x; i < 8192; i += 256) hs[i >> 9][i & 511] = h_all[t * 8192 + i];
    __syncthreads();
    const float4* hv = (const float4*)hs[lb];
    float d0 = 0.f, d1 = 0.f, d2 = 0.f;
#pragma unroll 4
    for (int k = 0; k < 128; k++) {
      float4 h4 = hv[k];
      float4 a4 = w0[k], b4 = w1[k], c4 = w2[k];
      d0 = fmaf(a4.x, h4.x, d0); d0 = fmaf(a4.y, h4.y, d0);
      d0 = fmaf(a4.z, h4.z, d0); d0 = fmaf(a4.w, h4.w, d0);
      d1 = fmaf(b4.x, h4.x, d1); d1 = fmaf(b4.y, h4.y, d1);
      d1 = fmaf(b4.z, h4.z, d1); d1 = fmaf(b4.w, h4.w, d1);
      d2 = fmaf(c4.x, h4.x, d2); d2 = fmaf(c4.y, h4.y, d2);
      d2 = fmaf(c4.z, h4.z, d2); d2 = fmaf(c4.w, h4.w, d2);
    }
    const float* gib = gi + ((size_t)t * 16 + lb) * 1536;
    float r = sigm(gib[jj] + d0 + bh0);
    float z = sigm(gib[jj + 512] + d1 + bh1);
    float n = tanhf(gib[jj + 1024] + r * (d2 + bh2));
    float hp = hs[lb][jj];
    h_all[(size_t)(t + 1) * 8192 + lb * 512 + jj] = (1.f - z) * n + z * hp;
    // grid barrier: release writes, signal, spin, acquire
    __syncthreads();
    if (threadIdx.x == 0) {
      __threadfence();
      __hip_atomic_fetch_add(bar, 1, __ATOMIC_RELEASE, __HIP_MEMORY_SCOPE_AGENT);
      while (__hip_atomic_load(bar, __ATOMIC_ACQUIRE, __HIP_MEMORY_SCOPE_AGENT) < 32 * (t + 1))
        __builtin_amdgcn_s_sleep(2);
    }
    __syncthreads();
    __threadfence();
  }
}

// ---------------- logits GEMM (bf16 MFMA): [512,512] x [32000,512]^T + bias ----------------
__global__ __launch_bounds__(256) void k_fc(const float* __restrict__ A,
    const u16* __restrict__ Bwb, const float* __restrict__ bias, float* __restrict__ out) {
  __shared__ u16 ash[128 * 136];
  int tid = threadIdx.x;
  int wave = tid >> 6;
  int lane = tid & 63;
  int quad = lane >> 4;
  int lr = lane & 15;
  int N0 = blockIdx.x * 256;
  int M0 = blockIdx.y * 128;
  f32x4 acc[8][4];
#pragma unroll
  for (int mf = 0; mf < 8; mf++)
#pragma unroll
    for (int nf = 0; nf < 4; nf++) acc[mf][nf] = (f32x4){0.f, 0.f, 0.f, 0.f};
  int arow = tid >> 1;
  int acol = (tid & 1) * 64;
  for (int kc = 0; kc < 512; kc += 128) {
#pragma unroll
    for (int j = 0; j < 16; j++) {
      float4 v = *(const float4*)(A + (size_t)(M0 + arow) * 512 + kc + acol + j * 4);
      union { u16 h[4]; uint2 u; } pk;
      pk.h[0] = f2bf(v.x); pk.h[1] = f2bf(v.y); pk.h[2] = f2bf(v.z); pk.h[3] = f2bf(v.w);
      *(uint2*)(&ash[arow * 136 + acol + j * 4]) = pk.u;
    }
    __syncthreads();
#pragma unroll
    for (int ks = 0; ks < 128; ks += 32) {
      bf16x8 af[8];
#pragma unroll
      for (int mf = 0; mf < 8; mf++)
        af[mf] = *(const bf16x8*)(&ash[(mf * 16 + lr) * 136 + ks + quad * 8]);
      bf16x8 bf[4];
#pragma unroll
      for (int nf = 0; nf < 4; nf++) {
        int n = N0 + wave * 64 + nf * 16 + lr;
        bf[nf] = *(const bf16x8*)(Bwb + (size_t)n * 512 + kc + ks + quad * 8);
      }
#pragma unroll
      for (int mf = 0; mf < 8; mf++)
#pragma unroll
        for (int nf = 0; nf < 4; nf++)
          acc[mf][nf] = __builtin_amdgcn_mfma_f32_16x16x32_bf16(af[mf], bf[nf], acc[mf][nf], 0, 0, 0);
    }
    __syncthreads();
  }
#pragma unroll
  for (int nf = 0; nf < 4; nf++) {
    int j = N0 + wave * 64 + nf * 16 + lr;
    float bv = bias[j];
#pragma unroll
    for (int mf = 0; mf < 8; mf++)
#pragma unroll
      for (int r = 0; r < 4; r++) {
        int m = M0 + mf * 16 + quad * 4 + r;   // m = t*16 + b
        int orow = (m & 15) * 32 + (m >> 4);   // out row = b*32 + t
        out[(size_t)orow * 32000 + j] = acc[mf][nf][r] + bv;
      }
  }
}

extern "C" void kernel_launch(void* const* d_in, const int* in_sizes, int n_in,
                              void* d_out, int out_size, void* d_ws, size_t ws_size,
                              hipStream_t stream) {
  const float* images  = (const float*)d_in[0];
  const int*   caps    = (const int*)d_in[1];
  const float* conv1_w = (const float*)d_in[2];
  const float* bn1_g   = (const float*)d_in[3];
  const float* bn1_b   = (const float*)d_in[4];
  const float* dw_w    = (const float*)d_in[5];
  const float* pw_w    = (const float*)d_in[6];
  const float* bn2_g   = (const float*)d_in[7];
  const float* bn2_b   = (const float*)d_in[8];
  const float* se1     = (const float*)d_in[9];
  const float* se2     = (const float*)d_in[10];
  const float* encw    = (const float*)d_in[11];
  const float* encb    = (const float*)d_in[12];
  const float* embed   = (const float*)d_in[13];
  const float* vw      = (const float*)d_in[16];
  const float* wih     = (const float*)d_in[17];
  const float* whh     = (const float*)d_in[18];
  const float* bih     = (const float*)d_in[19];
  const float* bhh     = (const float*)d_in[20];
  const float* fcw     = (const float*)d_in[21];
  const float* fcb     = (const float*)d_in[22];
  float* out = (float*)d_out;

  const bool big = ws_size >= (size_t)230 * 1000 * 1000;   // split-dw path needs ~214 MB

  char* ws = (char*)d_ws;
  size_t off = 0;
  auto alloc = [&](size_t bytes) {
    void* p = ws + off;
    off = (off + bytes + 255) & ~(size_t)255;
    return p;
  };
  u16* conv1out = (u16*)alloc((size_t)51380224 * 2);          // 98 MB
  u16* fcwb     = (u16*)conv1out;                             // alias (dead after dw/pwpass)
  u16* dwout    = big ? (u16*)alloc((size_t)51380224 * 2) : (u16*)nullptr;
  u16* bwb      = (u16*)alloc((size_t)131072 * 2);
  float* partials = (float*)alloc((size_t)3136 * 1024 * 4);
  float* p2     = (float*)alloc((size_t)64 * 1024 * 4);
  float* stats1 = (float*)alloc(512 * 4);
  float* h_all  = (float*)alloc((size_t)33 * 8192 * 4);
  float* bn1p   = (float*)alloc(512 * 4);
  float* bn2p   = (float*)alloc(1024 * 4);
  float* yb     = (float*)alloc(8192 * 4);
  float* ctxb   = (float*)alloc(8192 * 4);
  float* gi     = (float*)alloc((size_t)32 * 16 * 1536 * 4);
  int*   bar    = (int*)alloc(256);
  (void)in_sizes; (void)n_in; (void)out_size;

  hipMemsetAsync(stats1, 0, 512 * 4, stream);
  hipMemsetAsync(h_all, 0, 8192 * 4, stream);   // h0 = 0
  hipMemsetAsync(bar, 0, 256, stream);

  k_conv1<<<896, 256, 0, stream>>>(images, conv1_w, conv1out, stats1);
  k_bnfin<<<1, 256, 0, stream>>>(stats1, bn1_g, bn1_b, bn1p, 256, 1.f / (float)NSTAT);
  k_cvt4<<<128, 256, 0, stream>>>(pw_w, bwb, 32768);

  if (big) {
    k_dws<<<3136, 256, 0, stream>>>(conv1out, bn1p, dw_w, dwout);
    k_cvt4<<<16000, 256, 0, stream>>>(fcw, fcwb, 4096000);   // conv1out dead now
    k_pws<<<3136, 256, 0, stream>>>(dwout, bwb, partials, bn2p, 0);
    k_red1<<<64, 256, 0, stream>>>(partials, p2);
    k_red_bn2<<<2, 256, 0, stream>>>(p2, bn2_g, bn2_b, bn2p);
    k_pws<<<3136, 256, 0, stream>>>(dwout, bwb, partials, bn2p, 1);
  } else {
    k_pwpass<<<3136, 256, 0, stream>>>(conv1out, bn1p, dw_w, bwb, partials, bn2p, 0);
    k_red1<<<64, 256, 0, stream>>>(partials, p2);
    k_red_bn2<<<2, 256, 0, stream>>>(p2, bn2_g, bn2_b, bn2p);
    k_pwpass<<<3136, 256, 0, stream>>>(conv1out, bn1p, dw_w, bwb, partials, bn2p, 1);
    k_cvt4<<<16000, 256, 0, stream>>>(fcw, fcwb, 4096000);   // conv1out dead now
  }
  k_red_y<<<32, 256, 0, stream>>>(partials, yb);
  k_se<<<16, 256, 0, stream>>>(yb, se1, se2, encw, encb, vw, ctxb);
  dim3 ggi(32, 96);
  k_gi<<<ggi, 256, 0, stream>>>(caps, embed, ctxb, wih, bih, gi);
  k_gru_all<<<32, 256, 0, stream>>>(whh, bhh, gi, h_all, bar);
  dim3 gfc(125, 4);
  k_fc<<<gfc, 256, 0, stream>>>(h_all + 8192, fcwb, fcb, out);
}

// Round 6
// 1749.437 us; speedup vs baseline: 1.5259x; 1.5259x over previous
//
#include <hip/hip_runtime.h>

typedef unsigned int u32;
typedef unsigned short u16;
typedef short bf16x8 __attribute__((ext_vector_type(8)));
typedef float f32x4 __attribute__((ext_vector_type(4)));

#define S1 12544      // 112*112
#define NSTAT 200704  // 16*112*112
#define EPS 1e-5f
#define AP 264        // padded A-tile row length (fused path)

__device__ __forceinline__ u16 f2bf(float f) {
  union { float f; u32 u; } x; x.f = f;
  u32 r = x.u + 0x7fffu + ((x.u >> 16) & 1u);
  return (u16)(r >> 16);
}
__device__ __forceinline__ void bf2x2(u32 u, float& lo, float& hi) {
  union { u32 u; float f; } a, b;
  a.u = u << 16; b.u = u & 0xffff0000u;
  lo = a.f; hi = b.f;
}
__device__ __forceinline__ float sigm(float x) { return 1.f / (1.f + expf(-x)); }

// ---------------- conv1 (3->256, 3x3, stride2, pad1) + bn1 stats ----------------
#define CW 225
__global__ __launch_bounds__(256) void k_conv1(const float* __restrict__ img,
    const float* __restrict__ w, u16* __restrict__ out, float* __restrict__ stats) {
  int blk = blockIdx.x;
  int b = blk / 56, strip = blk - b * 56;
  int r0 = strip * 2;
  int c = threadIdx.x;
  __shared__ float simg[3 * 5 * CW];
  const float* ib = img + (size_t)b * 3 * 224 * 224;
  for (int i = c; i < 3 * 5 * CW; i += 256) {
    int ch = i / (5 * CW);
    int rem = i - ch * (5 * CW);
    int lr = rem / CW;
    int col = rem - lr * CW;
    int ih = 2 * r0 - 1 + lr;
    int iw = col - 1;
    float v = 0.f;
    if (ih >= 0 && ih < 224 && iw >= 0 && iw < 224) v = ib[((size_t)ch * 224 + ih) * 224 + iw];
    simg[i] = v;
  }
  float wr[27];
#pragma unroll
  for (int i = 0; i < 27; i++) wr[i] = w[c * 27 + i];
  __syncthreads();
  float s = 0.f, q = 0.f;
  for (int orow = 0; orow < 2; orow++) {
    int oh = r0 + orow;
    for (int ow = 0; ow < 112; ow++) {
      float acc = 0.f;
#pragma unroll
      for (int ch = 0; ch < 3; ch++)
#pragma unroll
        for (int dr = 0; dr < 3; dr++) {
          const float* rp = &simg[(ch * 5 + 2 * orow + dr) * CW + 2 * ow];
          acc = fmaf(wr[(ch * 3 + dr) * 3 + 0], rp[0], acc);
          acc = fmaf(wr[(ch * 3 + dr) * 3 + 1], rp[1], acc);
          acc = fmaf(wr[(ch * 3 + dr) * 3 + 2], rp[2], acc);
        }
      s += acc; q = fmaf(acc, acc, q);
      out[((size_t)(b * 112 + oh) * 112 + ow) * 256 + c] = f2bf(acc);
    }
  }
  atomicAdd(&stats[c], s);
  atomicAdd(&stats[256 + c], q);
}

// ---------------- bn finalize ----------------
__global__ void k_bnfin(const float* __restrict__ stats, const float* __restrict__ g,
                        const float* __restrict__ bb, float* __restrict__ par, int C, float invN) {
  int c = blockIdx.x * 256 + threadIdx.x;
  if (c < C) {
    float m = stats[c] * invN;
    float v = stats[C + c] * invN - m * m;
    float sc = g[c] * rsqrtf(v + EPS);
    par[c] = sc;
    par[C + c] = bb[c] - m * sc;
  }
}

// ---------------- fp32 -> bf16 x4 ----------------
__global__ void k_cvt4(const float* __restrict__ w, u16* __restrict__ o, int n4) {
  int i = blockIdx.x * 256 + threadIdx.x;
  if (i < n4) {
    float4 v = ((const float4*)w)[i];
    union { u16 h[4]; uint2 u; } pk;
    pk.h[0] = f2bf(v.x); pk.h[1] = f2bf(v.y); pk.h[2] = f2bf(v.z); pk.h[3] = f2bf(v.w);
    ((uint2*)o)[i] = pk.u;
  }
}

// ---- shared sliding-window dw macro (uses locals: ib, c4, sc, sh, act) ----
#define LD_COL(ohv, iwv, slot) do {                                          \
    int _oh = (ohv), _iw = (iwv);                                            \
  _Pragma("unroll")                                                          \
    for (int _dr = 0; _dr < 3; _dr++) {                                      \
      int _ih = _oh - 1 + _dr;                                               \
      float _x0 = 0.f, _x1 = 0.f, _x2 = 0.f, _x3 = 0.f;                      \
      if (_ih >= 0 && _ih < 112 && _iw >= 0 && _iw < 112) {                  \
        uint2 _v = *(const uint2*)(ib + ((size_t)(_ih * 112 + _iw)) * 256 + c4); \
        float _t0, _t1, _t2, _t3;                                            \
        bf2x2(_v.x, _t0, _t1); bf2x2(_v.y, _t2, _t3);                        \
        _x0 = fmaxf(fmaf(_t0, sc[0], sh[0]), 0.f);                           \
        _x1 = fmaxf(fmaf(_t1, sc[1], sh[1]), 0.f);                           \
        _x2 = fmaxf(fmaf(_t2, sc[2], sh[2]), 0.f);                           \
        _x3 = fmaxf(fmaf(_t3, sc[3], sh[3]), 0.f);                           \
      }                                                                      \
      act[_dr][slot][0] = _x0; act[_dr][slot][1] = _x1;                      \
      act[_dr][slot][2] = _x2; act[_dr][slot][3] = _x3;                      \
    }                                                                        \
  } while (0)

// ---------------- standalone dw kernel (big-ws path): conv1out -> dwout bf16 ----------------
__global__ __launch_bounds__(256) void k_dws(const u16* __restrict__ cin,
    const float* __restrict__ bn1p, const float* __restrict__ dww, u16* __restrict__ out) {
  int tid = threadIdx.x;
  int wave = tid >> 6, lane = tid & 63;
  int c4 = lane * 4;
  int m0 = blockIdx.x * 64;
  int bimg = blockIdx.x / 196;
  float sc[4], sh[4], w9[4][9];
#pragma unroll
  for (int cc = 0; cc < 4; cc++) {
    sc[cc] = bn1p[c4 + cc];
    sh[cc] = bn1p[256 + c4 + cc];
#pragma unroll
    for (int i = 0; i < 9; i++) w9[cc][i] = dww[(c4 + cc) * 9 + i];
  }
  const u16* ib = cin + (size_t)bimg * S1 * 256;
  float act[3][3][4];
#pragma unroll
  for (int pp = 0; pp < 16; pp++) {
    int p = wave * 16 + pp;
    int s = m0 + p - bimg * S1;
    int oh = s / 112, ow = s - oh * 112;
    if (pp == 0 || ow == 0) {
      LD_COL(oh, ow - 1, (pp + 0) % 3);
      LD_COL(oh, ow,     (pp + 1) % 3);
      LD_COL(oh, ow + 1, (pp + 2) % 3);
    } else {
      LD_COL(oh, ow + 1, (pp + 2) % 3);
    }
    float a0 = 0.f, a1 = 0.f, a2 = 0.f, a3 = 0.f;
#pragma unroll
    for (int dr = 0; dr < 3; dr++)
#pragma unroll
      for (int dc = 0; dc < 3; dc++) {
        const int sl = (pp + dc) % 3;
        const int wi = dr * 3 + dc;
        a0 = fmaf(w9[0][wi], act[dr][sl][0], a0);
        a1 = fmaf(w9[1][wi], act[dr][sl][1], a1);
        a2 = fmaf(w9[2][wi], act[dr][sl][2], a2);
        a3 = fmaf(w9[3][wi], act[dr][sl][3], a3);
      }
    union { u16 h[4]; uint2 v; } pk;
    pk.h[0] = f2bf(a0); pk.h[1] = f2bf(a1);
    pk.h[2] = f2bf(a2); pk.h[3] = f2bf(a3);
    *(uint2*)(out + (size_t)(m0 + p) * 256 + c4) = pk.v;
  }
}

// ---------------- streaming pw GEMM (big-ws path) ----------------
__global__ __launch_bounds__(256, 2) void k_pws(const u16* __restrict__ A,
    const u16* __restrict__ bwb, float* __restrict__ partials,
    const float* __restrict__ bn2p, int pass) {
  __shared__ u16 ash[64 * 256];
  int tid = threadIdx.x;
  int wave = tid >> 6, lane = tid & 63;
  int m0 = blockIdx.x * 64;
  {
    const char* gb = (const char*)(A + (size_t)m0 * 256);
    char* lb = (char*)ash;
#pragma unroll
    for (int i = 0; i < 8; i++) {
      int L = wave * 8192 + i * 1024 + lane * 16;
      int p = L >> 9;
      int gp = (L >> 4) & 31;
      int g = gp ^ (p & 7);
      uint4 v = *(const uint4*)(gb + (size_t)p * 512 + g * 16);
      *(uint4*)(lb + L) = v;
    }
  }
  __syncthreads();

  int quad = lane >> 4;
  int lr = lane & 15;
  int nbase = wave * 128;
  const char* ashb = (const char*)ash;
  f32x4 acc[4][8];
#pragma unroll
  for (int mt = 0; mt < 4; mt++)
#pragma unroll
    for (int nt = 0; nt < 8; nt++) acc[mt][nt] = (f32x4){0.f, 0.f, 0.f, 0.f};

#pragma unroll
  for (int ch = 0; ch < 8; ch++) {
    bf16x8 af[4];
#pragma unroll
    for (int mt = 0; mt < 4; mt++) {
      int row = mt * 16 + lr;
      int g = (ch * 4 + quad) ^ (row & 7);
      af[mt] = *(const bf16x8*)(ashb + row * 512 + g * 16);
    }
    bf16x8 bfr[8];
#pragma unroll
    for (int nt = 0; nt < 8; nt++)
      bfr[nt] = *(const bf16x8*)(bwb + (size_t)(nbase + nt * 16 + lr) * 256 + ch * 32 + quad * 8);
#pragma unroll
    for (int mt = 0; mt < 4; mt++)
#pragma unroll
      for (int nt = 0; nt < 8; nt++)
        acc[mt][nt] = __builtin_amdgcn_mfma_f32_16x16x32_bf16(af[mt], bfr[nt], acc[mt][nt], 0, 0, 0);
  }

  if (pass == 0) {
#pragma unroll
    for (int nt = 0; nt < 8; nt++) {
      float s = 0.f, q = 0.f;
#pragma unroll
      for (int mt = 0; mt < 4; mt++)
#pragma unroll
        for (int r = 0; r < 4; r++) {
          float v = acc[mt][nt][r];
          s += v; q = fmaf(v, v, q);
        }
      s += __shfl_xor(s, 16); s += __shfl_xor(s, 32);
      q += __shfl_xor(q, 16); q += __shfl_xor(q, 32);
      if (lane < 16) {
        int n = nbase + nt * 16 + lane;
        partials[(size_t)blockIdx.x * 1024 + n] = s;
        partials[(size_t)blockIdx.x * 1024 + 512 + n] = q;
      }
    }
  } else {
#pragma unroll
    for (int nt = 0; nt < 8; nt++) {
      int n = nbase + nt * 16 + lr;
      float scn = bn2p[n], shn = bn2p[512 + n];
      float s = 0.f;
#pragma unroll
      for (int mt = 0; mt < 4; mt++)
#pragma unroll
        for (int r = 0; r < 4; r++)
          s += fmaxf(fmaf(acc[mt][nt][r], scn, shn), 0.f);
      s += __shfl_xor(s, 16); s += __shfl_xor(s, 32);
      if (lane < 16)
        partials[(size_t)blockIdx.x * 512 + n] = s;
    }
  }
}

// ---------------- fused dw+pw (small-ws fallback) ----------------
__global__ __launch_bounds__(256, 2) void k_pwpass(
    const u16* __restrict__ conv1out, const float* __restrict__ bn1p,
    const float* __restrict__ dww, const u16* __restrict__ bwb,
    float* __restrict__ partials, const float* __restrict__ bn2p, int pass) {
  __shared__ u16 ash[64 * AP];
  int tid = threadIdx.x;
  int wave = tid >> 6;
  int lane = tid & 63;
  int m0 = blockIdx.x * 64;
  int bimg = blockIdx.x / 196;
  {
    int c4 = lane * 4;
    float sc[4], sh[4], w9[4][9];
#pragma unroll
    for (int cc = 0; cc < 4; cc++) {
      sc[cc] = bn1p[c4 + cc];
      sh[cc] = bn1p[256 + c4 + cc];
#pragma unroll
      for (int i = 0; i < 9; i++) w9[cc][i] = dww[(c4 + cc) * 9 + i];
    }
    const u16* ib = conv1out + (size_t)bimg * S1 * 256;
    float act[3][3][4];
#pragma unroll
    for (int pp = 0; pp < 16; pp++) {
      int p = wave * 16 + pp;
      int s = m0 + p - bimg * S1;
      int oh = s / 112, ow = s - oh * 112;
      if (pp == 0 || ow == 0) {
        LD_COL(oh, ow - 1, (pp + 0) % 3);
        LD_COL(oh, ow,     (pp + 1) % 3);
        LD_COL(oh, ow + 1, (pp + 2) % 3);
      } else {
        LD_COL(oh, ow + 1, (pp + 2) % 3);
      }
      float a0 = 0.f, a1 = 0.f, a2 = 0.f, a3 = 0.f;
#pragma unroll
      for (int dr = 0; dr < 3; dr++)
#pragma unroll
        for (int dc = 0; dc < 3; dc++) {
          const int sl = (pp + dc) % 3;
          const int wi = dr * 3 + dc;
          a0 = fmaf(w9[0][wi], act[dr][sl][0], a0);
          a1 = fmaf(w9[1][wi], act[dr][sl][1], a1);
          a2 = fmaf(w9[2][wi], act[dr][sl][2], a2);
          a3 = fmaf(w9[3][wi], act[dr][sl][3], a3);
        }
      union { u16 h[4]; uint2 v; } pk;
      pk.h[0] = f2bf(a0); pk.h[1] = f2bf(a1);
      pk.h[2] = f2bf(a2); pk.h[3] = f2bf(a3);
      *(uint2*)(&ash[p * AP + c4]) = pk.v;
    }
  }
  __syncthreads();
  int quad = lane >> 4;
  int lr = lane & 15;
  int nbase = wave * 128;
  f32x4 acc[4][8];
#pragma unroll
  for (int mt = 0; mt < 4; mt++)
#pragma unroll
    for (int nt = 0; nt < 8; nt++) acc[mt][nt] = (f32x4){0.f, 0.f, 0.f, 0.f};
  for (int kk = 0; kk < 256; kk += 32) {
    bf16x8 af[4];
#pragma unroll
    for (int mt = 0; mt < 4; mt++)
      af[mt] = *(const bf16x8*)(&ash[(mt * 16 + lr) * AP + kk + quad * 8]);
    bf16x8 bfr[8];
#pragma unroll
    for (int nt = 0; nt < 8; nt++)
      bfr[nt] = *(const bf16x8*)(bwb + (size_t)(nbase + nt * 16 + lr) * 256 + kk + quad * 8);
#pragma unroll
    for (int mt = 0; mt < 4; mt++)
#pragma unroll
      for (int nt = 0; nt < 8; nt++)
        acc[mt][nt] = __builtin_amdgcn_mfma_f32_16x16x32_bf16(af[mt], bfr[nt], acc[mt][nt], 0, 0, 0);
  }
  if (pass == 0) {
#pragma unroll
    for (int nt = 0; nt < 8; nt++) {
      float s = 0.f, q = 0.f;
#pragma unroll
      for (int mt = 0; mt < 4; mt++)
#pragma unroll
        for (int r = 0; r < 4; r++) {
          float v = acc[mt][nt][r];
          s += v; q = fmaf(v, v, q);
        }
      s += __shfl_xor(s, 16); s += __shfl_xor(s, 32);
      q += __shfl_xor(q, 16); q += __shfl_xor(q, 32);
      if (lane < 16) {
        int n = nbase + nt * 16 + lane;
        partials[(size_t)blockIdx.x * 1024 + n] = s;
        partials[(size_t)blockIdx.x * 1024 + 512 + n] = q;
      }
    }
  } else {
#pragma unroll
    for (int nt = 0; nt < 8; nt++) {
      int n = nbase + nt * 16 + lr;
      float scn = bn2p[n], shn = bn2p[512 + n];
      float s = 0.f;
#pragma unroll
      for (int mt = 0; mt < 4; mt++)
#pragma unroll
        for (int r = 0; r < 4; r++)
          s += fmaxf(fmaf(acc[mt][nt][r], scn, shn), 0.f);
      s += __shfl_xor(s, 16); s += __shfl_xor(s, 32);
      if (lane < 16)
        partials[(size_t)blockIdx.x * 512 + n] = s;
    }
  }
}

// ---------------- reductions ----------------
__global__ __launch_bounds__(256) void k_red1(const float* __restrict__ P, float* __restrict__ P2) {
  int blk = blockIdx.x;
  int t = threadIdx.x;
  float4 s = {0.f, 0.f, 0.f, 0.f};
  for (int r = 0; r < 49; r++) {
    float4 v = *(const float4*)(P + ((size_t)(blk * 49 + r)) * 1024 + t * 4);
    s.x += v.x; s.y += v.y; s.z += v.z; s.w += v.w;
  }
  *(float4*)(P2 + (size_t)blk * 1024 + t * 4) = s;
}

__global__ void k_red_bn2(const float* __restrict__ P2, const float* __restrict__ g,
                          const float* __restrict__ bb, float* __restrict__ par) {
  int c = blockIdx.x * 256 + threadIdx.x;
  float s = 0.f, q = 0.f;
  for (int i = 0; i < 64; i++) {
    s += P2[(size_t)i * 1024 + c];
    q += P2[(size_t)i * 1024 + 512 + c];
  }
  float m = s * (1.f / (float)NSTAT);
  float v = q * (1.f / (float)NSTAT) - m * m;
  float sc = g[c] * rsqrtf(v + EPS);
  par[c] = sc;
  par[512 + c] = bb[c] - m * sc;
}

__global__ void k_red_y(const float* __restrict__ P, float* __restrict__ yb) {
  int idx = blockIdx.x * 256 + threadIdx.x;
  int b = idx >> 9, c = idx & 511;
  float s = 0.f;
  for (int i = 0; i < 196; i++) s += P[(size_t)(b * 196 + i) * 512 + c];
  yb[idx] = s;
}

// ---------------- per-batch SE + enc_fc + ctx ----------------
__global__ __launch_bounds__(256) void k_se(const float* __restrict__ y,
    const float* __restrict__ se1, const float* __restrict__ se2,
    const float* __restrict__ encw, const float* __restrict__ encb,
    const float* __restrict__ vw, float* __restrict__ ctxb) {
  int b = blockIdx.x;
  int t = threadIdx.x;
  __shared__ __align__(16) float ybar[512];
  __shared__ __align__(16) float uu[128];
  __shared__ __align__(16) float ff[512];
  __shared__ __align__(16) float feats[512];
  for (int i = t; i < 512; i += 256) ybar[i] = y[b * 512 + i] * (1.f / 12544.f);
  __syncthreads();
  if (t < 128) {
    const float4* wr = (const float4*)(se1 + t * 512);
    const float4* xv = (const float4*)ybar;
    float a = 0.f;
    for (int k = 0; k < 128; k++) {
      float4 w4 = wr[k], x4 = xv[k];
      a = fmaf(w4.x, x4.x, a); a = fmaf(w4.y, x4.y, a);
      a = fmaf(w4.z, x4.z, a); a = fmaf(w4.w, x4.w, a);
    }
    uu[t] = fmaxf(a, 0.f);
  }
  __syncthreads();
  for (int c = t; c < 512; c += 256) {
    const float4* wr = (const float4*)(se2 + c * 128);
    const float4* xv = (const float4*)uu;
    float a = 0.f;
    for (int k = 0; k < 32; k++) {
      float4 w4 = wr[k], x4 = xv[k];
      a = fmaf(w4.x, x4.x, a); a = fmaf(w4.y, x4.y, a);
      a = fmaf(w4.z, x4.z, a); a = fmaf(w4.w, x4.w, a);
    }
    ff[c] = ybar[c] * sigm(a);
  }
  __syncthreads();
  for (int c = t; c < 512; c += 256) {
    const float4* wr = (const float4*)(encw + (size_t)c * 512);
    const float4* xv = (const float4*)ff;
    float a = encb[c];
    for (int k = 0; k < 128; k++) {
      float4 w4 = wr[k], x4 = xv[k];
      a = fmaf(w4.x, x4.x, a); a = fmaf(w4.y, x4.y, a);
      a = fmaf(w4.z, x4.z, a); a = fmaf(w4.w, x4.w, a);
    }
    feats[c] = a;
  }
  __syncthreads();
  for (int c = t; c < 512; c += 256) {
    const float4* wr = (const float4*)(vw + (size_t)c * 512);
    const float4* xv = (const float4*)feats;
    float a = 0.f;
    for (int k = 0; k < 128; k++) {
      float4 w4 = wr[k], x4 = xv[k];
      a = fmaf(w4.x, x4.x, a); a = fmaf(w4.y, x4.y, a);
      a = fmaf(w4.z, x4.z, a); a = fmaf(w4.w, x4.w, a);
    }
    ctxb[b * 512 + c] = a;
  }
}

// ---------------- gi = [emb_t ; ctx] @ wih^T + bih ----------------
__global__ __launch_bounds__(256) void k_gi(const int* __restrict__ caps,
    const float* __restrict__ embed, const float* __restrict__ ctxb,
    const float* __restrict__ wih, const float* __restrict__ bih, float* __restrict__ gi) {
  int tt = blockIdx.x;
  int jt = blockIdx.y;
  int lb = threadIdx.x >> 4;
  int lj = threadIdx.x & 15;
  int j = jt * 16 + lj;
  __shared__ __align__(16) float xx[16][1024];
  for (int i = threadIdx.x; i < 16 * 512; i += 256) {
    int bb = i >> 9, k = i & 511;
    int tok = caps[bb * 33 + tt];
    xx[bb][k] = embed[(size_t)tok * 512 + k];
    xx[bb][512 + k] = ctxb[bb * 512 + k];
  }
  __syncthreads();
  const float4* wr = (const float4*)(wih + (size_t)j * 1024);
  const float4* xv = (const float4*)xx[lb];
  float a = bih[j];
#pragma unroll 4
  for (int k = 0; k < 256; k++) {
    float4 w4 = wr[k], x4 = xv[k];
    a = fmaf(w4.x, x4.x, a); a = fmaf(w4.y, x4.y, a);
    a = fmaf(w4.z, x4.z, a); a = fmaf(w4.w, x4.w, a);
  }
  gi[((size_t)tt * 16 + lb) * 1536 + j] = a;
}

// ---------------- persistent GRU, weights in registers ----------------
// 64 blocks x 192 threads. Block g owns jj in [8g, 8g+8), ALL 3 gates (h-update
// is block-local; one grid barrier per step). Thread (s=tid/24, r=tid%24):
// gate=r/8, lj=r%8, seg s covers k in [64s, 64s+64). Weights held in 16 float4
// VGPRs for all 32 steps -> immune to the barrier's L1/L2 invalidation.
__global__ __launch_bounds__(192, 1) void k_gru_reg(const float* __restrict__ whh,
    const float* __restrict__ bhh, const float* __restrict__ gi,
    float* h_all, int* bar) {
  int g = blockIdx.x;
  int tid = threadIdx.x;
  int s = tid / 24;          // 0..7
  int r = tid - s * 24;      // 0..23
  int gate = r >> 3, lj = r & 7;
  int jj = g * 8 + lj;
  int R = gate * 512 + jj;
  float4 w[16];
  {
    const float4* wp = (const float4*)(whh + (size_t)R * 512 + s * 64);
#pragma unroll
    for (int i = 0; i < 16; i++) w[i] = wp[i];
  }
  __shared__ __align__(16) float hs[16][512];
  __shared__ float pr[8][24][16];   // [seg][row][batch]

  for (int t = 0; t < 32; t++) {
    // stage h_t
    {
      const float4* hp = (const float4*)(h_all + (size_t)t * 8192);
      float4* hd = (float4*)&hs[0][0];
      for (int i = tid; i < 2048; i += 192) hd[i] = hp[i];
    }
    __syncthreads();
    // per-thread partial dots: 16 batches x 64-wide segment
#pragma unroll
    for (int b = 0; b < 16; b++) {
      const float4* hv = (const float4*)&hs[b][s * 64];
      float a = 0.f;
#pragma unroll
      for (int k = 0; k < 16; k++) {
        float4 w4 = w[k], h4 = hv[k];
        a = fmaf(w4.x, h4.x, a); a = fmaf(w4.y, h4.y, a);
        a = fmaf(w4.z, h4.z, a); a = fmaf(w4.w, h4.w, a);
      }
      pr[s][r][b] = a;
    }
    __syncthreads();
    // combine gates + h update: threads 0..127, b=tid>>3, jl=tid&7
    if (tid < 128) {
      int b = tid >> 3, jl = tid & 7;
      int j = g * 8 + jl;
      float gh[3];
#pragma unroll
      for (int gg = 0; gg < 3; gg++) {
        int rr = gg * 8 + jl;
        float sum = bhh[gg * 512 + j];
#pragma unroll
        for (int ss = 0; ss < 8; ss++) sum += pr[ss][rr][b];
        gh[gg] = sum;
      }
      const float* gib = gi + ((size_t)t * 16 + b) * 1536;
      float rg = sigm(gib[j] + gh[0]);
      float z  = sigm(gib[j + 512] + gh[1]);
      float n  = tanhf(gib[j + 1024] + rg * gh[2]);
      float hp = hs[b][j];
      h_all[(size_t)(t + 1) * 8192 + b * 512 + j] = (1.f - z) * n + z * hp;
    }
    __syncthreads();   // h stores issued+drained (syncthreads waits vmcnt) before signal
    if (tid == 0) {
      __hip_atomic_fetch_add(bar, 1, __ATOMIC_RELEASE, __HIP_MEMORY_SCOPE_AGENT);
      int target = 64 * (t + 1);
      while (__hip_atomic_load(bar, __ATOMIC_RELAXED, __HIP_MEMORY_SCOPE_AGENT) < target)
        __builtin_amdgcn_s_sleep(1);
    }
    __syncthreads();
    __threadfence();   // acquire: next h_t reads must not hit stale cache
  }
}

// ---------------- logits GEMM (bf16 MFMA) ----------------
__global__ __launch_bounds__(256) void k_fc(const float* __restrict__ A,
    const u16* __restrict__ Bwb, const float* __restrict__ bias, float* __restrict__ out) {
  __shared__ u16 ash[128 * 136];
  int tid = threadIdx.x;
  int wave = tid >> 6;
  int lane = tid & 63;
  int quad = lane >> 4;
  int lr = lane & 15;
  int N0 = blockIdx.x * 256;
  int M0 = blockIdx.y * 128;
  f32x4 acc[8][4];
#pragma unroll
  for (int mf = 0; mf < 8; mf++)
#pragma unroll
    for (int nf = 0; nf < 4; nf++) acc[mf][nf] = (f32x4){0.f, 0.f, 0.f, 0.f};
  int arow = tid >> 1;
  int acol = (tid & 1) * 64;
  for (int kc = 0; kc < 512; kc += 128) {
#pragma unroll
    for (int j = 0; j < 16; j++) {
      float4 v = *(const float4*)(A + (size_t)(M0 + arow) * 512 + kc + acol + j * 4);
      union { u16 h[4]; uint2 u; } pk;
      pk.h[0] = f2bf(v.x); pk.h[1] = f2bf(v.y); pk.h[2] = f2bf(v.z); pk.h[3] = f2bf(v.w);
      *(uint2*)(&ash[arow * 136 + acol + j * 4]) = pk.u;
    }
    __syncthreads();
#pragma unroll
    for (int ks = 0; ks < 128; ks += 32) {
      bf16x8 af[8];
#pragma unroll
      for (int mf = 0; mf < 8; mf++)
        af[mf] = *(const bf16x8*)(&ash[(mf * 16 + lr) * 136 + ks + quad * 8]);
      bf16x8 bf[4];
#pragma unroll
      for (int nf = 0; nf < 4; nf++) {
        int n = N0 + wave * 64 + nf * 16 + lr;
        bf[nf] = *(const bf16x8*)(Bwb + (size_t)n * 512 + kc + ks + quad * 8);
      }
#pragma unroll
      for (int mf = 0; mf < 8; mf++)
#pragma unroll
        for (int nf = 0; nf < 4; nf++)
          acc[mf][nf] = __builtin_amdgcn_mfma_f32_16x16x32_bf16(af[mf], bf[nf], acc[mf][nf], 0, 0, 0);
    }
    __syncthreads();
  }
#pragma unroll
  for (int nf = 0; nf < 4; nf++) {
    int j = N0 + wave * 64 + nf * 16 + lr;
    float bv = bias[j];
#pragma unroll
    for (int mf = 0; mf < 8; mf++)
#pragma unroll
      for (int r = 0; r < 4; r++) {
        int m = M0 + mf * 16 + quad * 4 + r;   // m = t*16 + b
        int orow = (m & 15) * 32 + (m >> 4);   // out row = b*32 + t
        out[(size_t)orow * 32000 + j] = acc[mf][nf][r] + bv;
      }
  }
}

extern "C" void kernel_launch(void* const* d_in, const int* in_sizes, int n_in,
                              void* d_out, int out_size, void* d_ws, size_t ws_size,
                              hipStream_t stream) {
  const float* images  = (const float*)d_in[0];
  const int*   caps    = (const int*)d_in[1];
  const float* conv1_w = (const float*)d_in[2];
  const float* bn1_g   = (const float*)d_in[3];
  const float* bn1_b   = (const float*)d_in[4];
  const float* dw_w    = (const float*)d_in[5];
  const float* pw_w    = (const float*)d_in[6];
  const float* bn2_g   = (const float*)d_in[7];
  const float* bn2_b   = (const float*)d_in[8];
  const float* se1     = (const float*)d_in[9];
  const float* se2     = (const float*)d_in[10];
  const float* encw    = (const float*)d_in[11];
  const float* encb    = (const float*)d_in[12];
  const float* embed   = (const float*)d_in[13];
  const float* vw      = (const float*)d_in[16];
  const float* wih     = (const float*)d_in[17];
  const float* whh     = (const float*)d_in[18];
  const float* bih     = (const float*)d_in[19];
  const float* bhh     = (const float*)d_in[20];
  const float* fcw     = (const float*)d_in[21];
  const float* fcb     = (const float*)d_in[22];
  float* out = (float*)d_out;

  const bool big = ws_size >= (size_t)230 * 1000 * 1000;

  char* ws = (char*)d_ws;
  size_t off = 0;
  auto alloc = [&](size_t bytes) {
    void* p = ws + off;
    off = (off + bytes + 255) & ~(size_t)255;
    return p;
  };
  u16* conv1out = (u16*)alloc((size_t)51380224 * 2);
  u16* fcwb     = (u16*)conv1out;                       // alias (dead after dw/pwpass)
  u16* dwout    = big ? (u16*)alloc((size_t)51380224 * 2) : (u16*)nullptr;
  u16* bwb      = (u16*)alloc((size_t)131072 * 2);
  float* partials = (float*)alloc((size_t)3136 * 1024 * 4);
  float* p2     = (float*)alloc((size_t)64 * 1024 * 4);
  float* stats1 = (float*)alloc(512 * 4);
  float* h_all  = (float*)alloc((size_t)33 * 8192 * 4);
  float* bn1p   = (float*)alloc(512 * 4);
  float* bn2p   = (float*)alloc(1024 * 4);
  float* yb     = (float*)alloc(8192 * 4);
  float* ctxb   = (float*)alloc(8192 * 4);
  float* gi     = (float*)alloc((size_t)32 * 16 * 1536 * 4);
  int*   bar    = (int*)alloc(256);
  (void)in_sizes; (void)n_in; (void)out_size;

  hipMemsetAsync(stats1, 0, 512 * 4, stream);
  hipMemsetAsync(h_all, 0, 8192 * 4, stream);   // h0 = 0
  hipMemsetAsync(bar, 0, 256, stream);

  k_conv1<<<896, 256, 0, stream>>>(images, conv1_w, conv1out, stats1);
  k_bnfin<<<1, 256, 0, stream>>>(stats1, bn1_g, bn1_b, bn1p, 256, 1.f / (float)NSTAT);
  k_cvt4<<<128, 256, 0, stream>>>(pw_w, bwb, 32768);

  if (big) {
    k_dws<<<3136, 256, 0, stream>>>(conv1out, bn1p, dw_w, dwout);
    k_cvt4<<<16000, 256, 0, stream>>>(fcw, fcwb, 4096000);
    k_pws<<<3136, 256, 0, stream>>>(dwout, bwb, partials, bn2p, 0);
    k_red1<<<64, 256, 0, stream>>>(partials, p2);
    k_red_bn2<<<2, 256, 0, stream>>>(p2, bn2_g, bn2_b, bn2p);
    k_pws<<<3136, 256, 0, stream>>>(dwout, bwb, partials, bn2p, 1);
  } else {
    k_pwpass<<<3136, 256, 0, stream>>>(conv1out, bn1p, dw_w, bwb, partials, bn2p, 0);
    k_red1<<<64, 256, 0, stream>>>(partials, p2);
    k_red_bn2<<<2, 256, 0, stream>>>(p2, bn2_g, bn2_b, bn2p);
    k_pwpass<<<3136, 256, 0, stream>>>(conv1out, bn1p, dw_w, bwb, partials, bn2p, 1);
    k_cvt4<<<16000, 256, 0, stream>>>(fcw, fcwb, 4096000);
  }
  k_red_y<<<32, 256, 0, stream>>>(partials, yb);
  k_se<<<16, 256, 0, stream>>>(yb, se1, se2, encw, encb, vw, ctxb);
  dim3 ggi(32, 96);
  k_gi<<<ggi, 256, 0, stream>>>(caps, embed, ctxb, wih, bih, gi);
  k_gru_reg<<<64, 192, 0, stream>>>(whh, bhh, gi, h_all, bar);
  dim3 gfc(125, 4);
  k_fc<<<gfc, 256, 0, stream>>>(h_all + 8192, fcwb, fcb, out);
}